// Round 15
// baseline (225.664 us; speedup 1.0000x reference)
//
#include <hip/hip_runtime.h>
#include <hip/hip_bf16.h>
#include <math.h>

using bf16 = __hip_bfloat16;
typedef __attribute__((ext_vector_type(8))) short short8v;
typedef __attribute__((ext_vector_type(4))) float f32x4;
typedef __attribute__((ext_vector_type(16))) float f32x16;

#define DEV __device__ __forceinline__

// async global->LDS, 16B per lane. LDS dest must be wave-uniform base (HW adds lane*16).
DEV void load_lds16(const bf16* gsrc, bf16* ldst) {
  __builtin_amdgcn_global_load_lds((const __attribute__((address_space(1))) void*)gsrc,
                                   (__attribute__((address_space(3))) void*)ldst, 16, 0, 0);
}

// bijective chunked XCD swizzle (nwg must be %8==0)
DEV void swz8(int& bx, int& by, int gx, int gy) {
  const int n = gx * gy, c = n >> 3;
  int lin = bx + gx * by;
  lin = (lin & 7) * c + (lin >> 3);
  bx = lin % gx; by = lin / gx;
}

DEV unsigned pack2bf(float a, float b) {
  bf16 ba = __float2bfloat16(a), bb = __float2bfloat16(b);
  return (unsigned)*(unsigned short*)&ba | ((unsigned)*(unsigned short*)&bb << 16);
}

// ---------------- prep: weight transposes+converts AND LayerNorm1 in ONE launch ----------------
__global__ __launch_bounds__(256) void prep_kernel(
    const float* __restrict__ Wq, const float* __restrict__ Wk, const float* __restrict__ Wv,
    const float* __restrict__ Wo, const float* __restrict__ W1, const float* __restrict__ W2,
    bf16* __restrict__ WqT, bf16* __restrict__ WkT, bf16* __restrict__ WvT,
    bf16* __restrict__ WoT, bf16* __restrict__ W1T, bf16* __restrict__ W2T,
    const float* __restrict__ x, const float* __restrict__ ln1g, const float* __restrict__ ln1b,
    bf16* __restrict__ h) {
  __shared__ float tile[64][65];
  const int b = blockIdx.x;
  if (b >= 3072) {
    const int row = b - 3072, t = threadIdx.x;
    const float4 v = ((const float4*)(x + (size_t)row * 1024))[t];
    float s = v.x + v.y + v.z + v.w;
#pragma unroll
    for (int mm = 1; mm < 64; mm <<= 1) s += __shfl_xor(s, mm);
    __shared__ float r1[4], r2[4];
    if ((t & 63) == 0) r1[t >> 6] = s;
    __syncthreads();
    const float mean = (r1[0] + r1[1] + r1[2] + r1[3]) * (1.0f / 1024.0f);
    const float d0 = v.x - mean, d1 = v.y - mean, d2 = v.z - mean, d3 = v.w - mean;
    float s2 = d0 * d0 + d1 * d1 + d2 * d2 + d3 * d3;
#pragma unroll
    for (int mm = 1; mm < 64; mm <<= 1) s2 += __shfl_xor(s2, mm);
    if ((t & 63) == 0) r2[t >> 6] = s2;
    __syncthreads();
    const float var = (r2[0] + r2[1] + r2[2] + r2[3]) * (1.0f / 1024.0f);
    const float rinv = rsqrtf(var + 1e-5f);
    const int c = t * 4;
    bf16* o = h + (size_t)row * 1024 + c;
    o[0] = __float2bfloat16(d0 * rinv * ln1g[c + 0] + ln1b[c + 0]);
    o[1] = __float2bfloat16(d1 * rinv * ln1g[c + 1] + ln1b[c + 1]);
    o[2] = __float2bfloat16(d2 * rinv * ln1g[c + 2] + ln1b[c + 2]);
    o[3] = __float2bfloat16(d3 * rinv * ln1g[c + 3] + ln1b[c + 3]);
    return;
  }
  const float* W; bf16* WT; int K, N, n0, k0;
  if (b < 1024) {
    const int which = b >> 8, t = b & 255;
    W  = (which == 0) ? Wq  : (which == 1) ? Wk  : (which == 2) ? Wv  : Wo;
    WT = (which == 0) ? WqT : (which == 1) ? WkT : (which == 2) ? WvT : WoT;
    K = 1024; N = 1024; n0 = (t & 15) * 64; k0 = (t >> 4) * 64;
  } else if (b < 2048) {
    const int t = b - 1024;
    W = W1; WT = W1T; K = 1024; N = 4096; n0 = (t & 63) * 64; k0 = (t >> 6) * 64;
  } else {
    const int t = b - 2048;
    W = W2; WT = W2T; K = 4096; N = 1024; n0 = (t & 15) * 64; k0 = (t >> 4) * 64;
  }
  const int tx = threadIdx.x & 15, ty = threadIdx.x >> 4;
#pragma unroll
  for (int p = 0; p < 4; ++p) {
    int r = p * 16 + ty;
    float4 vv = *(const float4*)&W[(size_t)(k0 + r) * N + n0 + tx * 4];
    tile[r][tx * 4 + 0] = vv.x; tile[r][tx * 4 + 1] = vv.y;
    tile[r][tx * 4 + 2] = vv.z; tile[r][tx * 4 + 3] = vv.w;
  }
  __syncthreads();
#pragma unroll
  for (int p = 0; p < 4; ++p) {
    int n = p * 16 + ty;
    bf16* dst = WT + (size_t)(n0 + n) * K + k0 + tx * 4;
#pragma unroll
    for (int j = 0; j < 4; ++j) dst[j] = __float2bfloat16(tile[tx * 4 + j][n]);
  }
}

// ---------------- LayerNorm: fp32 [rows][1024] -> bf16 ----------------
__global__ __launch_bounds__(256) void ln_kernel(const float* __restrict__ x,
                                                 const float* __restrict__ g,
                                                 const float* __restrict__ b,
                                                 bf16* __restrict__ out) {
  const int row = blockIdx.x, t = threadIdx.x;
  const float4 v = ((const float4*)(x + (size_t)row * 1024))[t];
  float s = v.x + v.y + v.z + v.w;
#pragma unroll
  for (int mm = 1; mm < 64; mm <<= 1) s += __shfl_xor(s, mm);
  __shared__ float r1[4], r2[4];
  if ((t & 63) == 0) r1[t >> 6] = s;
  __syncthreads();
  const float mean = (r1[0] + r1[1] + r1[2] + r1[3]) * (1.0f / 1024.0f);
  const float d0 = v.x - mean, d1 = v.y - mean, d2 = v.z - mean, d3 = v.w - mean;
  float s2 = d0 * d0 + d1 * d1 + d2 * d2 + d3 * d3;
#pragma unroll
  for (int mm = 1; mm < 64; mm <<= 1) s2 += __shfl_xor(s2, mm);
  if ((t & 63) == 0) r2[t >> 6] = s2;
  __syncthreads();
  const float var = (r2[0] + r2[1] + r2[2] + r2[3]) * (1.0f / 1024.0f);
  const float rinv = rsqrtf(var + 1e-5f);
  const int c = t * 4;
  bf16* o = out + (size_t)row * 1024 + c;
  o[0] = __float2bfloat16(d0 * rinv * g[c + 0] + b[c + 0]);
  o[1] = __float2bfloat16(d1 * rinv * g[c + 1] + b[c + 1]);
  o[2] = __float2bfloat16(d2 * rinv * g[c + 2] + b[c + 2]);
  o[3] = __float2bfloat16(d3 * rinv * g[c + 3] + b[c + 3]);
}

// ---------------- gemm256: 256x256 tile, BK=32, 4-buffer deep pipeline, counted vmcnt ----------------
// EPI 0: merged-QKV; Q output (zz==0) pre-scaled by 1/sqrt(128) for attention.
template <int EPI>
__global__ __launch_bounds__(512, 2) void gemm256(
    const bf16* __restrict__ A, const bf16* __restrict__ BT,
    const float* __restrict__ bias0, const float* __restrict__ bias1, const float* __restrict__ bias2,
    void* __restrict__ outp, int M, int N, int K) {
  __shared__ bf16 As[4][256 * 32];
  __shared__ bf16 Bs[4][256 * 32];
  const int tid = threadIdx.x;
  const int w = tid >> 6, l = tid & 63;
  const int wm = w >> 2, wn = w & 3;
  const int c = l & 15, h4 = l >> 4;
  int bx = blockIdx.x, by = blockIdx.y;
  swz8(bx, by, gridDim.x, gridDim.y);
  const int m0 = by * 256, n0 = bx * 256;

  const float* bias;
  int zz = 0;
  if (EPI == 0) {
    zz = n0 >> 10;
    bias = ((zz == 0) ? bias0 : (zz == 1) ? bias1 : bias2) - (zz << 10);
  } else {
    bias = bias0;
  }

  const int rl = l >> 2;
  const int ch = (l & 3) * 8;
  const int nkt = K >> 5;

  f32x4 acc[8][4] = {};

  auto STAGE_A = [&](int t, int b) {
    const bf16* src = A + (size_t)(m0 + rl) * K + t * 32 + ch;
    load_lds16(src + (size_t)((w * 2 + 0) * 16) * K, &As[b][(w * 2 + 0) * 512]);
    load_lds16(src + (size_t)((w * 2 + 1) * 16) * K, &As[b][(w * 2 + 1) * 512]);
  };
  auto STAGE_B = [&](int t, int b) {
    const bf16* src = BT + (size_t)(n0 + rl) * K + t * 32 + ch;
    load_lds16(src + (size_t)((w * 2 + 0) * 16) * K, &Bs[b][(w * 2 + 0) * 512]);
    load_lds16(src + (size_t)((w * 2 + 1) * 16) * K, &Bs[b][(w * 2 + 1) * 512]);
  };

  STAGE_A(0, 0); STAGE_B(0, 0);
  STAGE_A(1, 1); STAGE_B(1, 1);
  STAGE_A(2, 2); STAGE_B(2, 2);
  asm volatile("s_waitcnt vmcnt(8)" ::: "memory");
  __builtin_amdgcn_sched_barrier(0);
  __builtin_amdgcn_s_barrier();

  for (int t = 0; t < nkt; ++t) {
    const bf16* Ab = &As[t & 3][0];
    const bf16* Bb = &Bs[t & 3][0];
    short8v a[4], b[4];
#pragma unroll
    for (int i = 0; i < 4; ++i)
      a[i] = *(const short8v*)&Ab[(wm * 128 + i * 16 + c) * 32 + h4 * 8];
#pragma unroll
    for (int i = 0; i < 4; ++i)
      b[i] = *(const short8v*)&Bb[(wn * 64 + i * 16 + c) * 32 + h4 * 8];
    if (t + 3 < nkt) STAGE_A(t + 3, (t + 3) & 3);
    asm volatile("s_waitcnt lgkmcnt(0)" ::: "memory");
    __builtin_amdgcn_sched_barrier(0);
    __builtin_amdgcn_s_setprio(1);
#pragma unroll
    for (int mi = 0; mi < 4; ++mi)
#pragma unroll
      for (int ni = 0; ni < 4; ++ni)
        acc[mi][ni] = __builtin_amdgcn_mfma_f32_16x16x32_bf16(a[mi], b[ni], acc[mi][ni], 0, 0, 0);
    __builtin_amdgcn_s_setprio(0);
#pragma unroll
    for (int i = 0; i < 4; ++i)
      a[i] = *(const short8v*)&Ab[(wm * 128 + 64 + i * 16 + c) * 32 + h4 * 8];
    if (t + 3 < nkt) STAGE_B(t + 3, (t + 3) & 3);
    asm volatile("s_waitcnt lgkmcnt(0)" ::: "memory");
    __builtin_amdgcn_sched_barrier(0);
    __builtin_amdgcn_s_setprio(1);
#pragma unroll
    for (int mi = 0; mi < 4; ++mi)
#pragma unroll
      for (int ni = 0; ni < 4; ++ni)
        acc[4 + mi][ni] = __builtin_amdgcn_mfma_f32_16x16x32_bf16(a[mi], b[ni], acc[4 + mi][ni], 0, 0, 0);
    __builtin_amdgcn_s_setprio(0);
    if (t < nkt - 3)       asm volatile("s_waitcnt vmcnt(8)" ::: "memory");
    else if (t == nkt - 3) asm volatile("s_waitcnt vmcnt(4)" ::: "memory");
    else                   asm volatile("s_waitcnt vmcnt(0)" ::: "memory");
    __builtin_amdgcn_sched_barrier(0);
    __builtin_amdgcn_s_barrier();
  }

#pragma unroll
  for (int mi = 0; mi < 8; ++mi) {
#pragma unroll
    for (int ni = 0; ni < 4; ++ni) {
#pragma unroll
      for (int r = 0; r < 4; ++r) {
        const int m = m0 + wm * 128 + mi * 16 + h4 * 4 + r;
        const int n = n0 + wn * 64 + ni * 16 + c;
        float vv = acc[mi][ni][r] + bias[n];
        if (EPI == 0) {
          if (zz == 0) vv *= 0.08838834764831845f;  // pre-scale Q for attention
          const int bb = m >> 11, ss = m & 2047;
          const int n1 = n - (zz << 10);
          const int hh = n1 >> 7, dd = n1 & 127;
          ((bf16*)outp)[(size_t)zz * 4194304 + (((size_t)bb * 8 + hh) * 2048 + ss) * 128 + dd] =
              __float2bfloat16(vv);
        } else {
          const size_t idx = (size_t)m * N + n;
          const float u = 0.7978845608028654f * (vv + 0.044715f * vv * vv * vv);
          const float tt = __expf(2.0f * u);
          const float th = 1.0f - 2.0f / (tt + 1.0f);
          ((bf16*)outp)[idx] = __float2bfloat16(0.5f * vv * (1.0f + th));
        }
      }
    }
  }
}

// ---------------- gemm_sk2 (Wo + FFN2): split-K=2, 4-buffer deep pipeline, counted vmcnt ----------------
__global__ __launch_bounds__(512, 1) void gemm_sk2(
    const bf16* __restrict__ A, const bf16* __restrict__ BT,
    const float* __restrict__ bias, const float* __restrict__ res, float* __restrict__ outp,
    int M, int N, int K) {
  __shared__ __align__(16) char lds_raw[131072];
  const int tid = threadIdx.x;
  const int w = tid >> 6, l = tid & 63;
  const int grp = w >> 2, wg = w & 3;
  const int wr = wg >> 1, wc = wg & 1;
  const int col = l & 15, hi = l >> 4;
  int bx = blockIdx.x, by = blockIdx.y;
  swz8(bx, by, gridDim.x, gridDim.y);
  const int m0 = by * 128, n0 = bx * 128;

  const int rl = l >> 2;
  const int ch = (l & 3) * 8;
  f32x4 acc[4][4] = {};

  const int KH = K >> 1;
  const int kbase = grp * KH;
  const int nkt = KH >> 5;

  auto ABUF = [&](int b) { return (bf16*)(lds_raw + grp * 65536 + b * 16384); };
  auto BBUF = [&](int b) { return (bf16*)(lds_raw + grp * 65536 + b * 16384 + 8192); };

  auto STAGE = [&](int t, int b) {
    const bf16* srcA = A + (size_t)(m0 + rl) * K + kbase + t * 32 + ch;
    const bf16* srcB = BT + (size_t)(n0 + rl) * K + kbase + t * 32 + ch;
    bf16* Ab = ABUF(b); bf16* Bb = BBUF(b);
    load_lds16(srcA + (size_t)((wg * 2 + 0) * 16) * K, Ab + (wg * 2 + 0) * 512);
    load_lds16(srcA + (size_t)((wg * 2 + 1) * 16) * K, Ab + (wg * 2 + 1) * 512);
    load_lds16(srcB + (size_t)((wg * 2 + 0) * 16) * K, Bb + (wg * 2 + 0) * 512);
    load_lds16(srcB + (size_t)((wg * 2 + 1) * 16) * K, Bb + (wg * 2 + 1) * 512);
  };

  STAGE(0, 0); STAGE(1, 1); STAGE(2, 2);
  asm volatile("s_waitcnt vmcnt(8)" ::: "memory");
  __builtin_amdgcn_sched_barrier(0);
  __builtin_amdgcn_s_barrier();

  for (int t = 0; t < nkt; ++t) {
    const bf16* Ab = ABUF(t & 3);
    const bf16* Bb = BBUF(t & 3);
    short8v af[4], bf_[4];
#pragma unroll
    for (int i = 0; i < 4; ++i) {
      af[i]  = *(const short8v*)&Ab[(wr * 64 + i * 16 + col) * 32 + hi * 8];
      bf_[i] = *(const short8v*)&Bb[(wc * 64 + i * 16 + col) * 32 + hi * 8];
    }
    if (t + 3 < nkt) STAGE(t + 3, (t + 3) & 3);
    asm volatile("s_waitcnt lgkmcnt(0)" ::: "memory");
    __builtin_amdgcn_sched_barrier(0);
    __builtin_amdgcn_s_setprio(1);
#pragma unroll
    for (int mi = 0; mi < 4; ++mi)
#pragma unroll
      for (int ni = 0; ni < 4; ++ni)
        acc[mi][ni] = __builtin_amdgcn_mfma_f32_16x16x32_bf16(af[mi], bf_[ni], acc[mi][ni], 0, 0, 0);
    __builtin_amdgcn_s_setprio(0);
    if (t < nkt - 3)       asm volatile("s_waitcnt vmcnt(8)" ::: "memory");
    else if (t == nkt - 3) asm volatile("s_waitcnt vmcnt(4)" ::: "memory");
    else                   asm volatile("s_waitcnt vmcnt(0)" ::: "memory");
    __builtin_amdgcn_sched_barrier(0);
    __builtin_amdgcn_s_barrier();
  }

  float* dump = (float*)lds_raw;  // [128][130]
  if (grp == 1) {
#pragma unroll
    for (int mi = 0; mi < 4; ++mi)
#pragma unroll
      for (int ni = 0; ni < 4; ++ni)
#pragma unroll
        for (int r = 0; r < 4; ++r)
          dump[(wr * 64 + mi * 16 + hi * 4 + r) * 130 + wc * 64 + ni * 16 + col] = acc[mi][ni][r];
  }
  __syncthreads();
  if (grp == 0) {
#pragma unroll
    for (int mi = 0; mi < 4; ++mi) {
#pragma unroll
      for (int ni = 0; ni < 4; ++ni) {
#pragma unroll
        for (int r = 0; r < 4; ++r) {
          const int lrow = wr * 64 + mi * 16 + hi * 4 + r;
          const int lcol = wc * 64 + ni * 16 + col;
          const int m = m0 + lrow, n = n0 + lcol;
          const size_t idx = (size_t)m * N + n;
          outp[idx] = res[idx] + acc[mi][ni][r] + dump[lrow * 130 + lcol] + bias[n];
        }
      }
    }
  }
}

// ---------------- causal flash attention v7: 32x32 quadrants, branch-free softmax, 2-chain QK ----------------
// 8 waves = 2 KV-split groups x (2 q-sub x 2 k-sub). Wave computes S^T quadrant [32k x 32q] via
// two independent chains of 4 mfma_32x32x16 (s_lo: d-chunks 0-3, s_hi: 4-7), summed after.
// Lane owns one q-row (lq = l&31): softmax = in-lane max/sum + 1 shfl(32), unconditional rescale.
// PV: O^T quadrant += mfma32(V^T, P^T), 4 independent chains of 2. 4-way flash merge at q-tile end.
// Q pre-scaled by 1/sqrt(128) in the QKV GEMM.
__global__ __launch_bounds__(512) void attn_kernel(const bf16* __restrict__ q,
                                                   const bf16* __restrict__ k,
                                                   const bf16* __restrict__ v,
                                                   bf16* __restrict__ y) {
  __shared__ __align__(16) char lds_raw[159744];
  int p = blockIdx.x, bh = blockIdx.y;
  swz8(p, bh, 16, 16);
  const int tid = threadIdx.x;
  const int w = tid >> 6, l = tid & 63;
  const int grp = w >> 2;          // KV-split group
  const int wg  = w & 3;           // staging role within group
  const int qs  = (w >> 1) & 1;    // q-subblock (32 rows)
  const int ks  = w & 1;           // k-subhalf (32 keys)
  const int lq  = l & 31;          // q row / MFMA row index
  const int lh  = l >> 5;          // 8-elem granule half

  const bf16* kbase = k + (size_t)bh * 2048 * 128;
  const bf16* vbase = v + (size_t)bh * 2048 * 128;
  const int bb = bh >> 3, hh = bh & 7;

  bf16* Psw = (bf16*)(lds_raw + 139264 + (size_t)w * 2560);  // [32 q][40 k] bf16

  // staging lane mapping (v4/v5-proven)
  const int klr = (l >> 4);
  const int kblk0 = l & 15;
  const int vr = (l & 31) * 2;
  const int vcb = (wg * 2 + (l >> 5)) * 16;

  for (int half = 0; half < 2; ++half) {
    const int qt = half ? p : (31 - p);
    const int q0 = qt * 64;
    const int T = qt + 1;
    const int n0 = (T + 1) >> 1;
    const int myn = grp ? (T >> 1) : n0;
    const int tb = grp ? n0 : 0;

    // Q registers: 8 granules of 8 bf16 (d = c*16 + lh*8 .. +7) for row q0+qs*32+lq
    short8v qf[8];
    const bf16* qp = q + ((size_t)bh * 2048 + q0 + qs * 32 + lq) * 128 + lh * 8;
#pragma unroll
    for (int c = 0; c < 8; ++c) qf[c] = *(const short8v*)(qp + c * 16);

    f32x16 o[4] = {};            // O^T: o[db][reg] = O[d=db*32+row(reg,lh)][q=lq]
    float mx = -1e20f, sm = 0.f;

    if (myn > 0) {
      bf16* Ks0 = (bf16*)(lds_raw + (size_t)(grp * 2 + 0) * 16384);
      bf16* Vt0 = (bf16*)(lds_raw + 65536 + (size_t)(grp * 2 + 0) * 18432);
#pragma unroll
      for (int j = 0; j < 4; ++j) {
        const int lr = j * 4 + klr;
        const int blk = kblk0 ^ (lr & 7);
        load_lds16(kbase + (size_t)(tb * 64 + wg * 16 + lr) * 128 + blk * 8,
                   Ks0 + wg * 2048 + j * 512);
      }
      const bf16* vsrc = vbase + (size_t)(tb * 64 + vr) * 128 + vcb;
      short8v v00 = *(const short8v*)vsrc;
      short8v v01 = *(const short8v*)(vsrc + 8);
      short8v v10 = *(const short8v*)(vsrc + 128);
      short8v v11 = *(const short8v*)(vsrc + 136);
#pragma unroll
      for (int i = 0; i < 8; ++i) {
        *(unsigned int*)&Vt0[(vcb + i) * 72 + vr] =
            ((unsigned int)(unsigned short)v00[i]) | (((unsigned int)(unsigned short)v10[i]) << 16);
        *(unsigned int*)&Vt0[(vcb + 8 + i) * 72 + vr] =
            ((unsigned int)(unsigned short)v01[i]) | (((unsigned int)(unsigned short)v11[i]) << 16);
      }
    }
    __syncthreads();

    for (int it = 0; it < n0; ++it) {
      const int cur = it & 1;
      const bool active = it < myn;
      const bool havenext = (it + 1) < myn;
      bf16* KsCur = (bf16*)(lds_raw + (size_t)(grp * 2 + cur) * 16384);
      bf16* KsNxt = (bf16*)(lds_raw + (size_t)(grp * 2 + (cur ^ 1)) * 16384);
      bf16* VtCur = (bf16*)(lds_raw + 65536 + (size_t)(grp * 2 + cur) * 18432);
      bf16* VtNxt = (bf16*)(lds_raw + 65536 + (size_t)(grp * 2 + (cur ^ 1)) * 18432);

      short8v v00, v01, v10, v11;
      if (havenext) {
        const int nt = tb + it + 1;
#pragma unroll
        for (int j = 0; j < 4; ++j) {
          const int lr = j * 4 + klr;
          const int blk = kblk0 ^ (lr & 7);
          load_lds16(kbase + (size_t)(nt * 64 + wg * 16 + lr) * 128 + blk * 8,
                     KsNxt + wg * 2048 + j * 512);
        }
        const bf16* vsrc = vbase + (size_t)(nt * 64 + vr) * 128 + vcb;
        v00 = *(const short8v*)vsrc;
        v01 = *(const short8v*)(vsrc + 8);
        v10 = *(const short8v*)(vsrc + 128);
        v11 = *(const short8v*)(vsrc + 136);
      }

      if (active) {
        const int ktile = tb + it;
        // ---- S^T quadrant: two independent chains of 4 mfma32 ----
        f32x16 s_lo = {}, s_hi = {};
        const int kr = ks * 32 + lq;
        const int swz = kr & 7;
        __builtin_amdgcn_s_setprio(1);
#pragma unroll
        for (int c = 0; c < 4; ++c) {
          short8v kf0 = *(const short8v*)&KsCur[kr * 128 + (((2 * c + lh) ^ swz) << 3)];
          short8v kf1 = *(const short8v*)&KsCur[kr * 128 + (((2 * (c + 4) + lh) ^ swz) << 3)];
          s_lo = __builtin_amdgcn_mfma_f32_32x32x16_bf16(kf0, qf[c], s_lo, 0, 0, 0);
          s_hi = __builtin_amdgcn_mfma_f32_32x32x16_bf16(kf1, qf[c + 4], s_hi, 0, 0, 0);
        }
        __builtin_amdgcn_s_setprio(0);
        f32x16 s = s_lo + s_hi;

        // ---- causal mask (branch-free) ----
        const bool diag = (ktile == qt);
        const int qloc = qs * 32 + lq;
#pragma unroll
        for (int reg = 0; reg < 16; ++reg) {
          const int kloc = ks * 32 + (reg & 3) + 8 * (reg >> 2) + 4 * lh;
          if (diag && (kloc > qloc)) s[reg] = -1e30f;
        }
        // ---- lane-local softmax (unconditional rescale) ----
        float t0 = fmaxf(fmaxf(s[0], s[1]), fmaxf(s[2], s[3]));
        float t1 = fmaxf(fmaxf(s[4], s[5]), fmaxf(s[6], s[7]));
        float t2 = fmaxf(fmaxf(s[8], s[9]), fmaxf(s[10], s[11]));
        float t3 = fmaxf(fmaxf(s[12], s[13]), fmaxf(s[14], s[15]));
        float t = fmaxf(fmaxf(t0, t1), fmaxf(t2, t3));
        t = fmaxf(t, __shfl_xor(t, 32));
        const float mn = fmaxf(mx, t);
        const float aa = __expf(mx - mn);
        float ps = 0.f;
        unsigned u[8];
#pragma unroll
        for (int rq = 0; rq < 4; ++rq) {
          const float p0 = __expf(s[rq * 4 + 0] - mn);
          const float p1 = __expf(s[rq * 4 + 1] - mn);
          const float p2 = __expf(s[rq * 4 + 2] - mn);
          const float p3 = __expf(s[rq * 4 + 3] - mn);
          ps += (p0 + p1) + (p2 + p3);
          u[rq * 2 + 0] = pack2bf(p0, p1);
          u[rq * 2 + 1] = pack2bf(p2, p3);
        }
        sm = sm * aa + ps;
        mx = mn;
        // ---- write P quadrant: P[q=lq][k = rq*8 + lh*4 + 0..3] ----
#pragma unroll
        for (int rq = 0; rq < 4; ++rq) {
          uint2 pk; pk.x = u[rq * 2]; pk.y = u[rq * 2 + 1];
          *(uint2*)&Psw[lq * 40 + rq * 8 + lh * 4] = pk;
        }
        // ---- rescale O ----
#pragma unroll
        for (int db = 0; db < 4; ++db) o[db] *= aa;
      }

      if (havenext) {
#pragma unroll
        for (int i = 0; i < 8; ++i) {
          *(unsigned int*)&VtNxt[(vcb + i) * 72 + vr] =
              ((unsigned int)(unsigned short)v00[i]) | (((unsigned int)(unsigned short)v10[i]) << 16);
          *(unsigned int*)&VtNxt[(vcb + 8 + i) * 72 + vr] =
              ((unsigned int)(unsigned short)v01[i]) | (((unsigned int)(unsigned short)v11[i]) << 16);
        }
      }

      if (active) {
        // ---- PV: O^T quadrant += mfma32(V^T, P^T), 4 independent chains of 2 ----
        asm volatile("s_waitcnt lgkmcnt(0)" ::: "memory");
        __builtin_amdgcn_s_setprio(1);
#pragma unroll
        for (int kc = 0; kc < 2; ++kc) {
          short8v pf = *(const short8v*)&Psw[lq * 40 + kc * 16 + lh * 8];
#pragma unroll
          for (int db = 0; db < 4; ++db) {
            short8v vf = *(const short8v*)&VtCur[(db * 32 + lq) * 72 + ks * 32 + kc * 16 + lh * 8];
            o[db] = __builtin_amdgcn_mfma_f32_32x32x16_bf16(vf, pf, o[db], 0, 0, 0);
          }
        }
        __builtin_amdgcn_s_setprio(0);
      }
      __syncthreads();
    }

    // ---- 4-way flash merge per q-block ----
    sm += __shfl_xor(sm, 32);  // total over this wave's 32-k quadrant per q

    float* smmx = (float*)(lds_raw + 139264);  // [8 waves][64]: sm[0..31], mx[32..63]
    if (l < 32) { smmx[w * 64 + l] = sm; smmx[w * 64 + 32 + l] = mx; }
    const bool merger = (grp == 0 && ks == 0);
    if (!merger) {
      const int slot = qs * 3 + (grp * 2 + ks - 1);  // (0,1)->0, (1,0)->1, (1,1)->2
      float* dst = (float*)(lds_raw + slot * 17408);
#pragma unroll
      for (int db = 0; db < 4; ++db) {
#pragma unroll
        for (int rq = 0; rq < 4; ++rq) {
          f32x4 vv;
          vv[0] = o[db][rq * 4 + 0]; vv[1] = o[db][rq * 4 + 1];
          vv[2] = o[db][rq * 4 + 2]; vv[3] = o[db][rq * 4 + 3];
          *(f32x4*)&dst[lq * 132 + db * 32 + rq * 8 + lh * 4] = vv;
        }
      }
    }
    __syncthreads();
    if (merger) {
      const int w01 = w + 1, w10 = 4 + qs * 2, w11 = 5 + qs * 2;
      const float sm01 = smmx[w01 * 64 + lq], mx01 = smmx[w01 * 64 + 32 + lq];
      const float sm10 = smmx[w10 * 64 + lq], mx10 = smmx[w10 * 64 + 32 + lq];
      const float sm11 = smmx[w11 * 64 + lq], mx11 = smmx[w11 * 64 + 32 + lq];
      const float M = fmaxf(fmaxf(mx, mx01), fmaxf(mx10, mx11));
      const float a00 = __expf(mx - M), a01 = __expf(mx01 - M);
      const float a10 = __expf(mx10 - M), a11 = __expf(mx11 - M);
      const float inv = 1.0f / (sm * a00 + sm01 * a01 + sm10 * a10 + sm11 * a11);
      const float* d01 = (const float*)(lds_raw + (qs * 3 + 0) * 17408);
      const float* d10 = (const float*)(lds_raw + (qs * 3 + 1) * 17408);
      const float* d11 = (const float*)(lds_raw + (qs * 3 + 2) * 17408);
      const int qg = q0 + qs * 32 + lq;
      bf16* yrow = y + ((size_t)bb * 2048 + qg) * 1024 + hh * 128;
#pragma unroll
      for (int db = 0; db < 4; ++db) {
#pragma unroll
        for (int rq = 0; rq < 4; ++rq) {
          const int off = lq * 132 + db * 32 + rq * 8 + lh * 4;
          const f32x4 v01 = *(const f32x4*)&d01[off];
          const f32x4 v10 = *(const f32x4*)&d10[off];
          const f32x4 v11 = *(const f32x4*)&d11[off];
          const float r0 = (o[db][rq * 4 + 0] * a00 + v01[0] * a01 + v10[0] * a10 + v11[0] * a11) * inv;
          const float r1 = (o[db][rq * 4 + 1] * a00 + v01[1] * a01 + v10[1] * a10 + v11[1] * a11) * inv;
          const float r2 = (o[db][rq * 4 + 2] * a00 + v01[2] * a01 + v10[2] * a10 + v11[2] * a11) * inv;
          const float r3 = (o[db][rq * 4 + 3] * a00 + v01[3] * a01 + v10[3] * a10 + v11[3] * a11) * inv;
          uint2 pk; pk.x = pack2bf(r0, r1); pk.y = pack2bf(r2, r3);
          *(uint2*)(yrow + db * 32 + rq * 8 + lh * 4) = pk;
        }
      }
    }
    __syncthreads();
  }
}

extern "C" void kernel_launch(void* const* d_in, const int* in_sizes, int n_in,
                              void* d_out, int out_size, void* d_ws, size_t ws_size,
                              hipStream_t stream) {
  const float* x    = (const float*)d_in[0];
  const float* ln1g = (const float*)d_in[1];
  const float* ln1b = (const float*)d_in[2];
  const float* ln2g = (const float*)d_in[3];
  const float* ln2b = (const float*)d_in[4];
  const float* Wq   = (const float*)d_in[5];
  const float* bq   = (const float*)d_in[6];
  const float* Wk   = (const float*)d_in[7];
  const float* bk   = (const float*)d_in[8];
  const float* Wv   = (const float*)d_in[9];
  const float* bv   = (const float*)d_in[10];
  const float* Wo   = (const float*)d_in[11];
  const float* bo   = (const float*)d_in[12];
  const float* W1   = (const float*)d_in[13];
  const float* b1   = (const float*)d_in[14];
  const float* W2   = (const float*)d_in[15];
  const float* b2   = (const float*)d_in[16];
  float* out = (float*)d_out;
  char* ws = (char*)d_ws;
  const size_t MB = 1024 * 1024;

  bf16* WqT = (bf16*)(ws + 0 * MB);   // [3072][1024] merged qkv starts here
  bf16* WkT = (bf16*)(ws + 2 * MB);
  bf16* WvT = (bf16*)(ws + 4 * MB);
  bf16* WoT = (bf16*)(ws + 6 * MB);
  bf16* W1T = (bf16*)(ws + 8 * MB);   // [4096][1024]
  bf16* W2T = (bf16*)(ws + 16 * MB);  // [1024][4096]
  bf16* h   = (bf16*)(ws + 24 * MB);
  bf16* qb  = (bf16*)(ws + 32 * MB);  // qkv base: q,k,v contiguous 8MB each
  bf16* kb  = (bf16*)(ws + 40 * MB);
  bf16* vb  = (bf16*)(ws + 48 * MB);
  bf16* y   = (bf16*)(ws + 56 * MB);
  bf16* g   = (bf16*)(ws + 32 * MB);
  float* x1 = (float*)(ws + 64 * MB);
  bf16* h2  = h;

  prep_kernel<<<7168, 256, 0, stream>>>(Wq, Wk, Wv, Wo, W1, W2, WqT, WkT, WvT, WoT, W1T, W2T,
                                        x, ln1g, ln1b, h);

  gemm256<0><<<dim3(12, 16), 512, 0, stream>>>(h, WqT, bq, bk, bv, qb, 4096, 3072, 1024);

  attn_kernel<<<dim3(16, 16), 512, 0, stream>>>(qb, kb, vb, y);

  gemm_sk2<<<dim3(8, 32), 512, 0, stream>>>(y, WoT, bo, x, x1, 4096, 1024, 1024);

  ln_kernel<<<4096, 256, 0, stream>>>(x1, ln2g, ln2b, h2);

  gemm256<2><<<dim3(16, 16), 512, 0, stream>>>(h2, W1T, b1, nullptr, nullptr, g,
                                               4096, 4096, 1024);

  gemm_sk2<<<dim3(8, 32), 512, 0, stream>>>(g, W2T, b2, x1, out, 4096, 1024, 4096);
}

// Round 16
// 216.584 us; speedup vs baseline: 1.0419x; 1.0419x over previous
//
#include <hip/hip_runtime.h>
#include <hip/hip_bf16.h>
#include <math.h>

using bf16 = __hip_bfloat16;
typedef __attribute__((ext_vector_type(8))) short short8v;
typedef __attribute__((ext_vector_type(4))) float f32x4;

#define DEV __device__ __forceinline__

// async global->LDS, 16B per lane. LDS dest must be wave-uniform base (HW adds lane*16).
DEV void load_lds16(const bf16* gsrc, bf16* ldst) {
  __builtin_amdgcn_global_load_lds((const __attribute__((address_space(1))) void*)gsrc,
                                   (__attribute__((address_space(3))) void*)ldst, 16, 0, 0);
}

// bijective chunked XCD swizzle (nwg must be %8==0)
DEV void swz8(int& bx, int& by, int gx, int gy) {
  const int n = gx * gy, c = n >> 3;
  int lin = bx + gx * by;
  lin = (lin & 7) * c + (lin >> 3);
  bx = lin % gx; by = lin / gx;
}

DEV unsigned pack2bf(float a, float b) {
  bf16 ba = __float2bfloat16(a), bb = __float2bfloat16(b);
  return (unsigned)*(unsigned short*)&ba | ((unsigned)*(unsigned short*)&bb << 16);
}

// ---------------- prep: weight transposes+converts AND LayerNorm1 in ONE launch ----------------
__global__ __launch_bounds__(256) void prep_kernel(
    const float* __restrict__ Wq, const float* __restrict__ Wk, const float* __restrict__ Wv,
    const float* __restrict__ Wo, const float* __restrict__ W1, const float* __restrict__ W2,
    bf16* __restrict__ WqT, bf16* __restrict__ WkT, bf16* __restrict__ WvT,
    bf16* __restrict__ WoT, bf16* __restrict__ W1T, bf16* __restrict__ W2T,
    const float* __restrict__ x, const float* __restrict__ ln1g, const float* __restrict__ ln1b,
    bf16* __restrict__ h) {
  __shared__ float tile[64][65];
  const int b = blockIdx.x;
  if (b >= 3072) {
    const int row = b - 3072, t = threadIdx.x;
    const float4 v = ((const float4*)(x + (size_t)row * 1024))[t];
    float s = v.x + v.y + v.z + v.w;
#pragma unroll
    for (int mm = 1; mm < 64; mm <<= 1) s += __shfl_xor(s, mm);
    __shared__ float r1[4], r2[4];
    if ((t & 63) == 0) r1[t >> 6] = s;
    __syncthreads();
    const float mean = (r1[0] + r1[1] + r1[2] + r1[3]) * (1.0f / 1024.0f);
    const float d0 = v.x - mean, d1 = v.y - mean, d2 = v.z - mean, d3 = v.w - mean;
    float s2 = d0 * d0 + d1 * d1 + d2 * d2 + d3 * d3;
#pragma unroll
    for (int mm = 1; mm < 64; mm <<= 1) s2 += __shfl_xor(s2, mm);
    if ((t & 63) == 0) r2[t >> 6] = s2;
    __syncthreads();
    const float var = (r2[0] + r2[1] + r2[2] + r2[3]) * (1.0f / 1024.0f);
    const float rinv = rsqrtf(var + 1e-5f);
    const int c = t * 4;
    bf16* o = h + (size_t)row * 1024 + c;
    o[0] = __float2bfloat16(d0 * rinv * ln1g[c + 0] + ln1b[c + 0]);
    o[1] = __float2bfloat16(d1 * rinv * ln1g[c + 1] + ln1b[c + 1]);
    o[2] = __float2bfloat16(d2 * rinv * ln1g[c + 2] + ln1b[c + 2]);
    o[3] = __float2bfloat16(d3 * rinv * ln1g[c + 3] + ln1b[c + 3]);
    return;
  }
  const float* W; bf16* WT; int K, N, n0, k0;
  if (b < 1024) {
    const int which = b >> 8, t = b & 255;
    W  = (which == 0) ? Wq  : (which == 1) ? Wk  : (which == 2) ? Wv  : Wo;
    WT = (which == 0) ? WqT : (which == 1) ? WkT : (which == 2) ? WvT : WoT;
    K = 1024; N = 1024; n0 = (t & 15) * 64; k0 = (t >> 4) * 64;
  } else if (b < 2048) {
    const int t = b - 1024;
    W = W1; WT = W1T; K = 1024; N = 4096; n0 = (t & 63) * 64; k0 = (t >> 6) * 64;
  } else {
    const int t = b - 2048;
    W = W2; WT = W2T; K = 4096; N = 1024; n0 = (t & 15) * 64; k0 = (t >> 4) * 64;
  }
  const int tx = threadIdx.x & 15, ty = threadIdx.x >> 4;
#pragma unroll
  for (int p = 0; p < 4; ++p) {
    int r = p * 16 + ty;
    float4 vv = *(const float4*)&W[(size_t)(k0 + r) * N + n0 + tx * 4];
    tile[r][tx * 4 + 0] = vv.x; tile[r][tx * 4 + 1] = vv.y;
    tile[r][tx * 4 + 2] = vv.z; tile[r][tx * 4 + 3] = vv.w;
  }
  __syncthreads();
#pragma unroll
  for (int p = 0; p < 4; ++p) {
    int n = p * 16 + ty;
    bf16* dst = WT + (size_t)(n0 + n) * K + k0 + tx * 4;
#pragma unroll
    for (int j = 0; j < 4; ++j) dst[j] = __float2bfloat16(tile[tx * 4 + j][n]);
  }
}

// ---------------- LayerNorm: fp32 [rows][1024] -> bf16 ----------------
__global__ __launch_bounds__(256) void ln_kernel(const float* __restrict__ x,
                                                 const float* __restrict__ g,
                                                 const float* __restrict__ b,
                                                 bf16* __restrict__ out) {
  const int row = blockIdx.x, t = threadIdx.x;
  const float4 v = ((const float4*)(x + (size_t)row * 1024))[t];
  float s = v.x + v.y + v.z + v.w;
#pragma unroll
  for (int mm = 1; mm < 64; mm <<= 1) s += __shfl_xor(s, mm);
  __shared__ float r1[4], r2[4];
  if ((t & 63) == 0) r1[t >> 6] = s;
  __syncthreads();
  const float mean = (r1[0] + r1[1] + r1[2] + r1[3]) * (1.0f / 1024.0f);
  const float d0 = v.x - mean, d1 = v.y - mean, d2 = v.z - mean, d3 = v.w - mean;
  float s2 = d0 * d0 + d1 * d1 + d2 * d2 + d3 * d3;
#pragma unroll
  for (int mm = 1; mm < 64; mm <<= 1) s2 += __shfl_xor(s2, mm);
  if ((t & 63) == 0) r2[t >> 6] = s2;
  __syncthreads();
  const float var = (r2[0] + r2[1] + r2[2] + r2[3]) * (1.0f / 1024.0f);
  const float rinv = rsqrtf(var + 1e-5f);
  const int c = t * 4;
  bf16* o = out + (size_t)row * 1024 + c;
  o[0] = __float2bfloat16(d0 * rinv * g[c + 0] + b[c + 0]);
  o[1] = __float2bfloat16(d1 * rinv * g[c + 1] + b[c + 1]);
  o[2] = __float2bfloat16(d2 * rinv * g[c + 2] + b[c + 2]);
  o[3] = __float2bfloat16(d3 * rinv * g[c + 3] + b[c + 3]);
}

// ---------------- gemm256: 256x256 tile, BK=32, 4-buffer deep pipeline, counted vmcnt ----------------
// EPI 0: merged-QKV; Q output (zz==0) pre-scaled by 1/sqrt(128) for attention.
template <int EPI>
__global__ __launch_bounds__(512, 2) void gemm256(
    const bf16* __restrict__ A, const bf16* __restrict__ BT,
    const float* __restrict__ bias0, const float* __restrict__ bias1, const float* __restrict__ bias2,
    void* __restrict__ outp, int M, int N, int K) {
  __shared__ bf16 As[4][256 * 32];
  __shared__ bf16 Bs[4][256 * 32];
  const int tid = threadIdx.x;
  const int w = tid >> 6, l = tid & 63;
  const int wm = w >> 2, wn = w & 3;
  const int c = l & 15, h4 = l >> 4;
  int bx = blockIdx.x, by = blockIdx.y;
  swz8(bx, by, gridDim.x, gridDim.y);
  const int m0 = by * 256, n0 = bx * 256;

  const float* bias;
  int zz = 0;
  if (EPI == 0) {
    zz = n0 >> 10;
    bias = ((zz == 0) ? bias0 : (zz == 1) ? bias1 : bias2) - (zz << 10);
  } else {
    bias = bias0;
  }

  const int rl = l >> 2;
  const int ch = (l & 3) * 8;
  const int nkt = K >> 5;

  f32x4 acc[8][4] = {};

  auto STAGE_A = [&](int t, int b) {
    const bf16* src = A + (size_t)(m0 + rl) * K + t * 32 + ch;
    load_lds16(src + (size_t)((w * 2 + 0) * 16) * K, &As[b][(w * 2 + 0) * 512]);
    load_lds16(src + (size_t)((w * 2 + 1) * 16) * K, &As[b][(w * 2 + 1) * 512]);
  };
  auto STAGE_B = [&](int t, int b) {
    const bf16* src = BT + (size_t)(n0 + rl) * K + t * 32 + ch;
    load_lds16(src + (size_t)((w * 2 + 0) * 16) * K, &Bs[b][(w * 2 + 0) * 512]);
    load_lds16(src + (size_t)((w * 2 + 1) * 16) * K, &Bs[b][(w * 2 + 1) * 512]);
  };

  STAGE_A(0, 0); STAGE_B(0, 0);
  STAGE_A(1, 1); STAGE_B(1, 1);
  STAGE_A(2, 2); STAGE_B(2, 2);
  asm volatile("s_waitcnt vmcnt(8)" ::: "memory");
  __builtin_amdgcn_sched_barrier(0);
  __builtin_amdgcn_s_barrier();

  for (int t = 0; t < nkt; ++t) {
    const bf16* Ab = &As[t & 3][0];
    const bf16* Bb = &Bs[t & 3][0];
    short8v a[4], b[4];
#pragma unroll
    for (int i = 0; i < 4; ++i)
      a[i] = *(const short8v*)&Ab[(wm * 128 + i * 16 + c) * 32 + h4 * 8];
#pragma unroll
    for (int i = 0; i < 4; ++i)
      b[i] = *(const short8v*)&Bb[(wn * 64 + i * 16 + c) * 32 + h4 * 8];
    if (t + 3 < nkt) STAGE_A(t + 3, (t + 3) & 3);
    asm volatile("s_waitcnt lgkmcnt(0)" ::: "memory");
    __builtin_amdgcn_sched_barrier(0);
    __builtin_amdgcn_s_setprio(1);
#pragma unroll
    for (int mi = 0; mi < 4; ++mi)
#pragma unroll
      for (int ni = 0; ni < 4; ++ni)
        acc[mi][ni] = __builtin_amdgcn_mfma_f32_16x16x32_bf16(a[mi], b[ni], acc[mi][ni], 0, 0, 0);
    __builtin_amdgcn_s_setprio(0);
#pragma unroll
    for (int i = 0; i < 4; ++i)
      a[i] = *(const short8v*)&Ab[(wm * 128 + 64 + i * 16 + c) * 32 + h4 * 8];
    if (t + 3 < nkt) STAGE_B(t + 3, (t + 3) & 3);
    asm volatile("s_waitcnt lgkmcnt(0)" ::: "memory");
    __builtin_amdgcn_sched_barrier(0);
    __builtin_amdgcn_s_setprio(1);
#pragma unroll
    for (int mi = 0; mi < 4; ++mi)
#pragma unroll
      for (int ni = 0; ni < 4; ++ni)
        acc[4 + mi][ni] = __builtin_amdgcn_mfma_f32_16x16x32_bf16(a[mi], b[ni], acc[4 + mi][ni], 0, 0, 0);
    __builtin_amdgcn_s_setprio(0);
    if (t < nkt - 3)       asm volatile("s_waitcnt vmcnt(8)" ::: "memory");
    else if (t == nkt - 3) asm volatile("s_waitcnt vmcnt(4)" ::: "memory");
    else                   asm volatile("s_waitcnt vmcnt(0)" ::: "memory");
    __builtin_amdgcn_sched_barrier(0);
    __builtin_amdgcn_s_barrier();
  }

#pragma unroll
  for (int mi = 0; mi < 8; ++mi) {
#pragma unroll
    for (int ni = 0; ni < 4; ++ni) {
#pragma unroll
      for (int r = 0; r < 4; ++r) {
        const int m = m0 + wm * 128 + mi * 16 + h4 * 4 + r;
        const int n = n0 + wn * 64 + ni * 16 + c;
        float vv = acc[mi][ni][r] + bias[n];
        if (EPI == 0) {
          if (zz == 0) vv *= 0.08838834764831845f;  // pre-scale Q for attention
          const int bb = m >> 11, ss = m & 2047;
          const int n1 = n - (zz << 10);
          const int hh = n1 >> 7, dd = n1 & 127;
          ((bf16*)outp)[(size_t)zz * 4194304 + (((size_t)bb * 8 + hh) * 2048 + ss) * 128 + dd] =
              __float2bfloat16(vv);
        } else {
          const size_t idx = (size_t)m * N + n;
          const float u = 0.7978845608028654f * (vv + 0.044715f * vv * vv * vv);
          const float tt = __expf(2.0f * u);
          const float th = 1.0f - 2.0f / (tt + 1.0f);
          ((bf16*)outp)[idx] = __float2bfloat16(0.5f * vv * (1.0f + th));
        }
      }
    }
  }
}

// ---------------- gemm_sk2 (Wo + FFN2): split-K=2, 4-buffer deep pipeline, counted vmcnt ----------------
__global__ __launch_bounds__(512, 1) void gemm_sk2(
    const bf16* __restrict__ A, const bf16* __restrict__ BT,
    const float* __restrict__ bias, const float* __restrict__ res, float* __restrict__ outp,
    int M, int N, int K) {
  __shared__ __align__(16) char lds_raw[131072];
  const int tid = threadIdx.x;
  const int w = tid >> 6, l = tid & 63;
  const int grp = w >> 2, wg = w & 3;
  const int wr = wg >> 1, wc = wg & 1;
  const int col = l & 15, hi = l >> 4;
  int bx = blockIdx.x, by = blockIdx.y;
  swz8(bx, by, gridDim.x, gridDim.y);
  const int m0 = by * 128, n0 = bx * 128;

  const int rl = l >> 2;
  const int ch = (l & 3) * 8;
  f32x4 acc[4][4] = {};

  const int KH = K >> 1;
  const int kbase = grp * KH;
  const int nkt = KH >> 5;

  auto ABUF = [&](int b) { return (bf16*)(lds_raw + grp * 65536 + b * 16384); };
  auto BBUF = [&](int b) { return (bf16*)(lds_raw + grp * 65536 + b * 16384 + 8192); };

  auto STAGE = [&](int t, int b) {
    const bf16* srcA = A + (size_t)(m0 + rl) * K + kbase + t * 32 + ch;
    const bf16* srcB = BT + (size_t)(n0 + rl) * K + kbase + t * 32 + ch;
    bf16* Ab = ABUF(b); bf16* Bb = BBUF(b);
    load_lds16(srcA + (size_t)((wg * 2 + 0) * 16) * K, Ab + (wg * 2 + 0) * 512);
    load_lds16(srcA + (size_t)((wg * 2 + 1) * 16) * K, Ab + (wg * 2 + 1) * 512);
    load_lds16(srcB + (size_t)((wg * 2 + 0) * 16) * K, Bb + (wg * 2 + 0) * 512);
    load_lds16(srcB + (size_t)((wg * 2 + 1) * 16) * K, Bb + (wg * 2 + 1) * 512);
  };

  STAGE(0, 0); STAGE(1, 1); STAGE(2, 2);
  asm volatile("s_waitcnt vmcnt(8)" ::: "memory");
  __builtin_amdgcn_sched_barrier(0);
  __builtin_amdgcn_s_barrier();

  for (int t = 0; t < nkt; ++t) {
    const bf16* Ab = ABUF(t & 3);
    const bf16* Bb = BBUF(t & 3);
    short8v af[4], bf_[4];
#pragma unroll
    for (int i = 0; i < 4; ++i) {
      af[i]  = *(const short8v*)&Ab[(wr * 64 + i * 16 + col) * 32 + hi * 8];
      bf_[i] = *(const short8v*)&Bb[(wc * 64 + i * 16 + col) * 32 + hi * 8];
    }
    if (t + 3 < nkt) STAGE(t + 3, (t + 3) & 3);
    asm volatile("s_waitcnt lgkmcnt(0)" ::: "memory");
    __builtin_amdgcn_sched_barrier(0);
    __builtin_amdgcn_s_setprio(1);
#pragma unroll
    for (int mi = 0; mi < 4; ++mi)
#pragma unroll
      for (int ni = 0; ni < 4; ++ni)
        acc[mi][ni] = __builtin_amdgcn_mfma_f32_16x16x32_bf16(af[mi], bf_[ni], acc[mi][ni], 0, 0, 0);
    __builtin_amdgcn_s_setprio(0);
    if (t < nkt - 3)       asm volatile("s_waitcnt vmcnt(8)" ::: "memory");
    else if (t == nkt - 3) asm volatile("s_waitcnt vmcnt(4)" ::: "memory");
    else                   asm volatile("s_waitcnt vmcnt(0)" ::: "memory");
    __builtin_amdgcn_sched_barrier(0);
    __builtin_amdgcn_s_barrier();
  }

  float* dump = (float*)lds_raw;  // [128][130]
  if (grp == 1) {
#pragma unroll
    for (int mi = 0; mi < 4; ++mi)
#pragma unroll
      for (int ni = 0; ni < 4; ++ni)
#pragma unroll
        for (int r = 0; r < 4; ++r)
          dump[(wr * 64 + mi * 16 + hi * 4 + r) * 130 + wc * 64 + ni * 16 + col] = acc[mi][ni][r];
  }
  __syncthreads();
  if (grp == 0) {
#pragma unroll
    for (int mi = 0; mi < 4; ++mi) {
#pragma unroll
      for (int ni = 0; ni < 4; ++ni) {
#pragma unroll
        for (int r = 0; r < 4; ++r) {
          const int lrow = wr * 64 + mi * 16 + hi * 4 + r;
          const int lcol = wc * 64 + ni * 16 + col;
          const int m = m0 + lrow, n = n0 + lcol;
          const size_t idx = (size_t)m * N + n;
          outp[idx] = res[idx] + acc[mi][ni][r] + dump[lrow * 130 + lcol] + bias[n];
        }
      }
    }
  }
}

// ---------------- causal flash attention v5 (R14-proven): swapped QK^T, lane-local softmax ----------------
// S^T = mfma(K, Q): lane (col,hi) holds S[q=col][k=kg*16+hi*4+r] (Q pre-scaled by 1/sqrt(128)).
// Branch-free softmax: unconditional rescale (co-schedules with MFMA). PV: O^T = mfma(V^T, P^T).
__global__ __launch_bounds__(512) void attn_kernel(const bf16* __restrict__ q,
                                                   const bf16* __restrict__ k,
                                                   const bf16* __restrict__ v,
                                                   bf16* __restrict__ y) {
  __shared__ __align__(16) char lds_raw[157696];
  int p = blockIdx.x, bh = blockIdx.y;
  swz8(p, bh, 16, 16);
  const int tid = threadIdx.x;
  const int w = tid >> 6, l = tid & 63;
  const int grp = w >> 2, wg = w & 3;
  const int col = l & 15, hi = l >> 4;

  const bf16* kbase = k + (size_t)bh * 2048 * 128;
  const bf16* vbase = v + (size_t)bh * 2048 * 128;
  const int bb = bh >> 3, hh = bh & 7;

  bf16* Psw = (bf16*)(lds_raw + 139264 + (size_t)w * 2304);  // [16 q][72 k] bf16

  const int klr = (l >> 4);
  const int kblk0 = l & 15;
  const int vr = (l & 31) * 2;
  const int vcb = (wg * 2 + (l >> 5)) * 16;

  for (int half = 0; half < 2; ++half) {
    const int qt = half ? p : (31 - p);
    const int q0 = qt * 64;
    const int T = qt + 1;
    const int n0 = (T + 1) >> 1;
    const int myn = grp ? (T >> 1) : n0;
    const int tb = grp ? n0 : 0;

    short8v qf[4];
    const bf16* qp = q + ((size_t)bh * 2048 + q0 + wg * 16 + col) * 128;
#pragma unroll
    for (int c = 0; c < 4; ++c) qf[c] = *(const short8v*)(qp + c * 32 + hi * 8);

    f32x4 o[8] = {};          // O^T: o[db][r] = O[q=col][d = db*16 + hi*4 + r]
    float mx = -1e30f, sm = 0.f;  // per-lane scalars for q=col

    if (myn > 0) {
      bf16* Ks0 = (bf16*)(lds_raw + (size_t)(grp * 2 + 0) * 16384);
      bf16* Vt0 = (bf16*)(lds_raw + 65536 + (size_t)(grp * 2 + 0) * 18432);
#pragma unroll
      for (int j = 0; j < 4; ++j) {
        const int lr = j * 4 + klr;
        const int blk = kblk0 ^ (lr & 7);
        load_lds16(kbase + (size_t)(tb * 64 + wg * 16 + lr) * 128 + blk * 8,
                   Ks0 + wg * 2048 + j * 512);
      }
      const bf16* vsrc = vbase + (size_t)(tb * 64 + vr) * 128 + vcb;
      short8v v00 = *(const short8v*)vsrc;
      short8v v01 = *(const short8v*)(vsrc + 8);
      short8v v10 = *(const short8v*)(vsrc + 128);
      short8v v11 = *(const short8v*)(vsrc + 136);
#pragma unroll
      for (int i = 0; i < 8; ++i) {
        *(unsigned int*)&Vt0[(vcb + i) * 72 + vr] =
            ((unsigned int)(unsigned short)v00[i]) | (((unsigned int)(unsigned short)v10[i]) << 16);
        *(unsigned int*)&Vt0[(vcb + 8 + i) * 72 + vr] =
            ((unsigned int)(unsigned short)v01[i]) | (((unsigned int)(unsigned short)v11[i]) << 16);
      }
    }
    __syncthreads();

    for (int it = 0; it < n0; ++it) {
      const int cur = it & 1;
      const bool active = it < myn;
      const bool havenext = (it + 1) < myn;
      bf16* KsCur = (bf16*)(lds_raw + (size_t)(grp * 2 + cur) * 16384);
      bf16* KsNxt = (bf16*)(lds_raw + (size_t)(grp * 2 + (cur ^ 1)) * 16384);
      bf16* VtCur = (bf16*)(lds_raw + 65536 + (size_t)(grp * 2 + cur) * 18432);
      bf16* VtNxt = (bf16*)(lds_raw + 65536 + (size_t)(grp * 2 + (cur ^ 1)) * 18432);

      short8v v00, v01, v10, v11;
      if (havenext) {
        const int nt = tb + it + 1;
#pragma unroll
        for (int j = 0; j < 4; ++j) {
          const int lr = j * 4 + klr;
          const int blk = kblk0 ^ (lr & 7);
          load_lds16(kbase + (size_t)(nt * 64 + wg * 16 + lr) * 128 + blk * 8,
                     KsNxt + wg * 2048 + j * 512);
        }
        const bf16* vsrc = vbase + (size_t)(nt * 64 + vr) * 128 + vcb;
        v00 = *(const short8v*)vsrc;
        v01 = *(const short8v*)(vsrc + 8);
        v10 = *(const short8v*)(vsrc + 128);
        v11 = *(const short8v*)(vsrc + 136);
      }

      if (active) {
        const int ktile = tb + it;
        // ---- S^T = mfma(K, Q): lane holds S[q=col][k=kg*16+hi*4+r] ----
        f32x4 s[4] = {};
        __builtin_amdgcn_s_setprio(1);
#pragma unroll
        for (int c4 = 0; c4 < 4; ++c4) {
#pragma unroll
          for (int kg = 0; kg < 4; ++kg) {
            const int kr = kg * 16 + col;
            short8v kf = *(const short8v*)&KsCur[kr * 128 + ((c4 * 32 + hi * 8) ^ ((col & 7) << 3))];
            s[kg] = __builtin_amdgcn_mfma_f32_16x16x32_bf16(kf, qf[c4], s[kg], 0, 0, 0);
          }
        }
        __builtin_amdgcn_s_setprio(0);

        // ---- causal mask fused into write-back (branch-free, R11 form) ----
        const bool diag = (ktile == qt);
        const int qloc = wg * 16 + col;
#pragma unroll
        for (int kg = 0; kg < 4; ++kg) {
#pragma unroll
          for (int r = 0; r < 4; ++r) {
            float a = s[kg][r];
            if (diag && (kg * 16 + hi * 4 + r > qloc)) a = -1e30f;
            s[kg][r] = a;
          }
        }
        // ---- lane-local softmax for q=col (unconditional rescale) ----
        f32x4 m4;
#pragma unroll
        for (int r = 0; r < 4; ++r)
          m4[r] = fmaxf(fmaxf(s[0][r], s[1][r]), fmaxf(s[2][r], s[3][r]));
        float t = fmaxf(fmaxf(m4[0], m4[1]), fmaxf(m4[2], m4[3]));
        t = fmaxf(t, __shfl_xor(t, 16));
        t = fmaxf(t, __shfl_xor(t, 32));
        const float mn = fmaxf(mx, t);
        const float aa = __expf(mx - mn);
        float ps = 0.f;
        unsigned pk0[4], pk1[4];
#pragma unroll
        for (int kg = 0; kg < 4; ++kg) {
          const float p0 = __expf(s[kg][0] - mn);
          const float p1 = __expf(s[kg][1] - mn);
          const float p2 = __expf(s[kg][2] - mn);
          const float p3 = __expf(s[kg][3] - mn);
          ps += (p0 + p1) + (p2 + p3);
          pk0[kg] = pack2bf(p0, p1);
          pk1[kg] = pack2bf(p2, p3);
        }
        ps += __shfl_xor(ps, 16);
        ps += __shfl_xor(ps, 32);
        sm = sm * aa + ps;
        mx = mn;
        // ---- write P[q=col][k] (8B pairs) ----
#pragma unroll
        for (int kg = 0; kg < 4; ++kg) {
          uint2 pk; pk.x = pk0[kg]; pk.y = pk1[kg];
          *(uint2*)&Psw[col * 72 + kg * 16 + hi * 4] = pk;
        }
        // ---- rescale O ----
#pragma unroll
        for (int db = 0; db < 8; ++db) {
          o[db][0] *= aa; o[db][1] *= aa; o[db][2] *= aa; o[db][3] *= aa;
        }
      }

      if (havenext) {
#pragma unroll
        for (int i = 0; i < 8; ++i) {
          *(unsigned int*)&VtNxt[(vcb + i) * 72 + vr] =
              ((unsigned int)(unsigned short)v00[i]) | (((unsigned int)(unsigned short)v10[i]) << 16);
          *(unsigned int*)&VtNxt[(vcb + 8 + i) * 72 + vr] =
              ((unsigned int)(unsigned short)v01[i]) | (((unsigned int)(unsigned short)v11[i]) << 16);
        }
      }

      if (active) {
        // ---- PV: O^T += mfma(V^T, P^T) ----
        asm volatile("s_waitcnt lgkmcnt(0)" ::: "memory");
        __builtin_amdgcn_s_setprio(1);
#pragma unroll
        for (int ks = 0; ks < 2; ++ks) {
          short8v pf = *(const short8v*)&Psw[col * 72 + ks * 32 + hi * 8];
#pragma unroll
          for (int db = 0; db < 8; ++db) {
            short8v vf = *(const short8v*)&VtCur[(db * 16 + col) * 72 + ks * 32 + hi * 8];
            o[db] = __builtin_amdgcn_mfma_f32_16x16x32_bf16(vf, pf, o[db], 0, 0, 0);
          }
        }
        __builtin_amdgcn_s_setprio(0);
      }
      __syncthreads();
    }

    // ---- merge group partials (reuses K region) ----
    if (grp == 1) {
      float* Mo = (float*)(lds_raw + (size_t)wg * 8448);        // [16 q][132 d]
      float* Ml = (float*)(lds_raw + 33792 + (size_t)wg * 128); // [16 q][2]
#pragma unroll
      for (int db = 0; db < 8; ++db)
        *(f32x4*)&Mo[col * 132 + db * 16 + hi * 4] = o[db];
      if (hi == 0) { Ml[col * 2] = mx; Ml[col * 2 + 1] = sm; }
    }
    __syncthreads();
    if (grp == 0) {
      const float* Mo = (const float*)(lds_raw + (size_t)wg * 8448);
      const float* Ml = (const float*)(lds_raw + 33792 + (size_t)wg * 128);
      const float m1 = Ml[col * 2], l1 = Ml[col * 2 + 1];
      const float M = fmaxf(mx, m1);
      const float a0 = __expf(mx - M);
      const float a1 = __expf(m1 - M);
      const float inv = 1.0f / (sm * a0 + l1 * a1);
      const int qg = q0 + wg * 16 + col;
      bf16* yrow = y + ((size_t)bb * 2048 + qg) * 1024 + hh * 128;
#pragma unroll
      for (int db = 0; db < 8; ++db) {
        f32x4 rd = *(const f32x4*)&Mo[col * 132 + db * 16 + hi * 4];
        const unsigned w0 = pack2bf((o[db][0] * a0 + rd[0] * a1) * inv,
                                    (o[db][1] * a0 + rd[1] * a1) * inv);
        const unsigned w1 = pack2bf((o[db][2] * a0 + rd[2] * a1) * inv,
                                    (o[db][3] * a0 + rd[3] * a1) * inv);
        uint2 pk; pk.x = w0; pk.y = w1;
        *(uint2*)(yrow + db * 16 + hi * 4) = pk;
      }
    }
    __syncthreads();
  }
}

extern "C" void kernel_launch(void* const* d_in, const int* in_sizes, int n_in,
                              void* d_out, int out_size, void* d_ws, size_t ws_size,
                              hipStream_t stream) {
  const float* x    = (const float*)d_in[0];
  const float* ln1g = (const float*)d_in[1];
  const float* ln1b = (const float*)d_in[2];
  const float* ln2g = (const float*)d_in[3];
  const float* ln2b = (const float*)d_in[4];
  const float* Wq   = (const float*)d_in[5];
  const float* bq   = (const float*)d_in[6];
  const float* Wk   = (const float*)d_in[7];
  const float* bk   = (const float*)d_in[8];
  const float* Wv   = (const float*)d_in[9];
  const float* bv   = (const float*)d_in[10];
  const float* Wo   = (const float*)d_in[11];
  const float* bo   = (const float*)d_in[12];
  const float* W1   = (const float*)d_in[13];
  const float* b1   = (const float*)d_in[14];
  const float* W2   = (const float*)d_in[15];
  const float* b2   = (const float*)d_in[16];
  float* out = (float*)d_out;
  char* ws = (char*)d_ws;
  const size_t MB = 1024 * 1024;

  bf16* WqT = (bf16*)(ws + 0 * MB);   // [3072][1024] merged qkv starts here
  bf16* WkT = (bf16*)(ws + 2 * MB);
  bf16* WvT = (bf16*)(ws + 4 * MB);
  bf16* WoT = (bf16*)(ws + 6 * MB);
  bf16* W1T = (bf16*)(ws + 8 * MB);   // [4096][1024]
  bf16* W2T = (bf16*)(ws + 16 * MB);  // [1024][4096]
  bf16* h   = (bf16*)(ws + 24 * MB);
  bf16* qb  = (bf16*)(ws + 32 * MB);  // qkv base: q,k,v contiguous 8MB each
  bf16* kb  = (bf16*)(ws + 40 * MB);
  bf16* vb  = (bf16*)(ws + 48 * MB);
  bf16* y   = (bf16*)(ws + 56 * MB);
  bf16* g   = (bf16*)(ws + 32 * MB);
  float* x1 = (float*)(ws + 64 * MB);
  bf16* h2  = h;

  prep_kernel<<<7168, 256, 0, stream>>>(Wq, Wk, Wv, Wo, W1, W2, WqT, WkT, WvT, WoT, W1T, W2T,
                                        x, ln1g, ln1b, h);

  gemm256<0><<<dim3(12, 16), 512, 0, stream>>>(h, WqT, bq, bk, bv, qb, 4096, 3072, 1024);

  attn_kernel<<<dim3(16, 16), 512, 0, stream>>>(qb, kb, vb, y);

  gemm_sk2<<<dim3(8, 32), 512, 0, stream>>>(y, WoT, bo, x, x1, 4096, 1024, 1024);

  ln_kernel<<<4096, 256, 0, stream>>>(x1, ln2g, ln2b, h2);

  gemm256<2><<<dim3(16, 16), 512, 0, stream>>>(h2, W1T, b1, nullptr, nullptr, g,
                                               4096, 4096, 1024);

  gemm_sk2<<<dim3(8, 32), 512, 0, stream>>>(g, W2T, b2, x1, out, 4096, 1024, 4096);
}